// Round 9
// baseline (717.741 us; speedup 1.0000x reference)
//
#include <hip/hip_runtime.h>

#define SEQ   512
#define BATCH 64
#define HID   1024
#define NX    8

#define NBLK  512   // 8 b-groups x 64 blocks
#define GSZ   64    // blocks per barrier group
#define SGC   8     // s-groups per batch (phase B), 64 rows each
#define SB    8
#define NBAT  8     // 8*8 = 64 rows per phase-B block

// ---------------------------------------------------------------------------
// WVT[h][n] = WV[n][h]
// ---------------------------------------------------------------------------
__global__ __launch_bounds__(256) void transpose_k(
    const float* __restrict__ in, float* __restrict__ outT)
{
    __shared__ float tile[32][33];
    const int bx = blockIdx.x * 32, by = blockIdx.y * 32;
    const int tx = threadIdx.x & 31, ty = threadIdx.x >> 5;
    #pragma unroll
    for (int r = ty; r < 32; r += 8)
        tile[r][tx] = in[(size_t)(by + r) * HID + bx + tx];
    __syncthreads();
    #pragma unroll
    for (int r = ty; r < 32; r += 8)
        outT[(size_t)(bx + r) * HID + by + tx] = tile[tx][r];
}

// ---------------------------------------------------------------------------
// 64-block group barrier (device/agent scope). ctr/gen zeroed by memsetAsync
// each launch. Relaxed spin (no L2-inv per poll) + one acquire on exit.
// Bounded spin = anti-hang safety net only.
// ---------------------------------------------------------------------------
__device__ __forceinline__ void bgroup_barrier(unsigned* ctr, unsigned* gen)
{
    __syncthreads();
    if (threadIdx.x == 0) {
        const unsigned g0 = __hip_atomic_load(gen, __ATOMIC_RELAXED, __HIP_MEMORY_SCOPE_AGENT);
        const unsigned a  = __hip_atomic_fetch_add(ctr, 1u, __ATOMIC_ACQ_REL, __HIP_MEMORY_SCOPE_AGENT);
        if (a == (unsigned)(GSZ - 1)) {
            __hip_atomic_store(ctr, 0u, __ATOMIC_RELAXED, __HIP_MEMORY_SCOPE_AGENT);
            __hip_atomic_store(gen, g0 + 1u, __ATOMIC_RELEASE, __HIP_MEMORY_SCOPE_AGENT);
        } else {
            unsigned spins = 0u;
            while (__hip_atomic_load(gen, __ATOMIC_RELAXED, __HIP_MEMORY_SCOPE_AGENT) == g0) {
                if (++spins > (1u << 25)) break;   // safety net
            }
            (void)__hip_atomic_load(gen, __ATOMIC_ACQUIRE, __HIP_MEMORY_SCOPE_AGENT);
        }
    }
    __syncthreads();
}

// ---------------------------------------------------------------------------
// Persistent per-b-group kernel. bid = bg*64 + gi.
// Per step t: A) yp[b,jc,n] partial GEMV x.WK (b-blocked, weights reused 8x)
//             B) flash attention (online m,l) over 64 rows, zp/ml
//             C) z = global-rescale(zp); opp[b,hc,n] partial GEMV z.WVT
// Hand-offs summed during consumer staging. Barriers only within the group.
// ---------------------------------------------------------------------------
__global__ __launch_bounds__(256, 2) void genxs_persistent(
    const float* __restrict__ hidden, const float* __restrict__ q,
    const float* __restrict__ WK, const float* __restrict__ WVT,
    const float* __restrict__ bV, float* __restrict__ out,
    float* __restrict__ yp, float* __restrict__ zp,
    float* __restrict__ ml, float* __restrict__ opp,
    unsigned* __restrict__ bar)
{
    const int bid = blockIdx.x;
    const int bg  = bid >> 6;          // 0..7
    const int gi  = bid & 63;          // 0..63
    const int tid = threadIdx.x;
    const int lane = tid & 63, w = tid >> 6;

    unsigned* ctr = bar + (size_t)bg * 32;
    unsigned* gen = ctr + 16;

    __shared__ float xs[128][8];       // staged x / z, transposed [elem][bl]
    __shared__ float red[2][8][128];   // cross-half reduce
    __shared__ float part[4][SB];
    __shared__ float mls[128];

    const int a_nc = gi >> 3, a_jc = gi & 7;
    const int b_sg = gi >> 3, b_bl = gi & 7;
    const int c_nc = gi >> 3, c_hc = gi & 7;

    for (int t = 1; t < NX; t++) {
        // ================= phase A: yp = partial x.WK =================
        {
            for (int i = tid; i < 1024; i += 256) {
                const int bl = i >> 7, jl = i & 127;
                const int b = bg * 8 + bl;
                const int j = a_jc * 128 + jl;
                float v;
                if (t == 1) {
                    v = q[(size_t)b * HID + j];
                } else {
                    v = bV[j];
                    const float* __restrict__ p = opp + ((size_t)b * 8) * HID + j;
                    #pragma unroll
                    for (int hc = 0; hc < 8; hc++) v += p[(size_t)hc * HID];
                }
                xs[jl][bl] = v;
                if (a_nc == 0)
                    out[((size_t)(b * NX + t - 1)) * HID + j] = v;
            }
            __syncthreads();

            const int nl = tid & 127, jh = tid >> 7;
            const int n = a_nc * 128 + nl;
            const float* __restrict__ wp =
                WK + ((size_t)(a_jc * 128 + jh * 64)) * HID + n;
            float acc[8] = {};
            #pragma unroll 4
            for (int jj = 0; jj < 64; jj++) {
                const float wv = wp[(size_t)jj * HID];
                const float4 xa = *(const float4*)&xs[jh * 64 + jj][0];
                const float4 xb = *(const float4*)&xs[jh * 64 + jj][4];
                acc[0] += xa.x * wv; acc[1] += xa.y * wv;
                acc[2] += xa.z * wv; acc[3] += xa.w * wv;
                acc[4] += xb.x * wv; acc[5] += xb.y * wv;
                acc[6] += xb.z * wv; acc[7] += xb.w * wv;
            }
            #pragma unroll
            for (int bl = 0; bl < 8; bl++) red[jh][bl][nl] = acc[bl];
            __syncthreads();
            for (int i = tid; i < 1024; i += 256) {
                const int bl = i >> 7, nl2 = i & 127;
                const int b = bg * 8 + bl;
                yp[((size_t)(b * 8 + a_jc)) * HID + a_nc * 128 + nl2] =
                    red[0][bl][nl2] + red[1][bl][nl2];
            }
        }
        bgroup_barrier(ctr, gen);

        // ================= phase B: flash attention, 64 rows =================
        {
            const int b = bg * 8 + b_bl;
            const int h4 = tid * 4;
            float4 yv = {0.f, 0.f, 0.f, 0.f};
            #pragma unroll
            for (int jc = 0; jc < 8; jc++) {
                const float4 v = *(const float4*)(yp + ((size_t)(b * 8 + jc)) * HID + h4);
                yv.x += v.x; yv.y += v.y; yv.z += v.z; yv.w += v.w;
            }
            float m = -1e30f, l = 0.f;
            float4 acc = {0.f, 0.f, 0.f, 0.f};
            for (int bb = 0; bb < NBAT; bb++) {
                float4 hv[SB]; float p[SB];
                #pragma unroll
                for (int r = 0; r < SB; r++) {
                    const int s = b_sg * 64 + bb * SB + r;
                    hv[r] = *(const float4*)(hidden + ((size_t)s * BATCH + b) * HID + h4);
                    p[r] = hv[r].x * yv.x + hv[r].y * yv.y
                         + hv[r].z * yv.z + hv[r].w * yv.w;
                }
                #pragma unroll
                for (int r = 0; r < SB; r++) {
                    float sgm = p[r];
                    #pragma unroll
                    for (int off = 32; off; off >>= 1) sgm += __shfl_xor(sgm, off);
                    if (lane == 0) part[w][r] = sgm;
                }
                __syncthreads();
                float sc[SB], mb = -1e30f;
                #pragma unroll
                for (int r = 0; r < SB; r++) {
                    sc[r] = part[0][r] + part[1][r] + part[2][r] + part[3][r];
                    mb = fmaxf(mb, sc[r]);
                }
                __syncthreads();
                const float newm  = fmaxf(m, mb);
                const float scale = __expf(m - newm);
                l *= scale;
                acc.x *= scale; acc.y *= scale; acc.z *= scale; acc.w *= scale;
                #pragma unroll
                for (int r = 0; r < SB; r++) {
                    const float wexp = __expf(sc[r] - newm);
                    l += wexp;
                    acc.x += wexp * hv[r].x; acc.y += wexp * hv[r].y;
                    acc.z += wexp * hv[r].z; acc.w += wexp * hv[r].w;
                }
                m = newm;
            }
            *(float4*)(zp + ((size_t)(b * SGC + b_sg)) * HID + h4) = acc;
            if (tid == 0) {
                ml[(b * SGC + b_sg) * 2 + 0] = m;
                ml[(b * SGC + b_sg) * 2 + 1] = l;
            }
        }
        bgroup_barrier(ctr, gen);

        // ================= phase C: opp = partial rescale(zp).WVT =================
        {
            if (tid < 128) mls[tid] = ml[bg * 128 + tid];
            __syncthreads();
            {
                const int bl = tid >> 5, hl0 = (tid & 31) * 4;
                const int b = bg * 8 + bl;
                const float* mb_ = &mls[bl * 16];
                float M = -1e30f;
                #pragma unroll
                for (int g = 0; g < 8; g++) M = fmaxf(M, mb_[2 * g]);
                float es[8], L = 0.f;
                #pragma unroll
                for (int g = 0; g < 8; g++) {
                    es[g] = __expf(mb_[2 * g] - M);
                    L += mb_[2 * g + 1] * es[g];
                }
                const float invL = 1.0f / L;
                float4 z4 = {0.f, 0.f, 0.f, 0.f};
                #pragma unroll
                for (int g = 0; g < 8; g++) {
                    const float4 v = *(const float4*)(
                        zp + ((size_t)(b * SGC + g)) * HID + c_hc * 128 + hl0);
                    z4.x += es[g] * v.x; z4.y += es[g] * v.y;
                    z4.z += es[g] * v.z; z4.w += es[g] * v.w;
                }
                xs[hl0 + 0][bl] = z4.x * invL;
                xs[hl0 + 1][bl] = z4.y * invL;
                xs[hl0 + 2][bl] = z4.z * invL;
                xs[hl0 + 3][bl] = z4.w * invL;
            }
            __syncthreads();

            const int nl = tid & 127, hh2 = tid >> 7;
            const int n = c_nc * 128 + nl;
            const float* __restrict__ wp =
                WVT + ((size_t)(c_hc * 128 + hh2 * 64)) * HID + n;
            float acc[8] = {};
            #pragma unroll 4
            for (int hh = 0; hh < 64; hh++) {
                const float wv = wp[(size_t)hh * HID];
                const float4 xa = *(const float4*)&xs[hh2 * 64 + hh][0];
                const float4 xb = *(const float4*)&xs[hh2 * 64 + hh][4];
                acc[0] += xa.x * wv; acc[1] += xa.y * wv;
                acc[2] += xa.z * wv; acc[3] += xa.w * wv;
                acc[4] += xb.x * wv; acc[5] += xb.y * wv;
                acc[6] += xb.z * wv; acc[7] += xb.w * wv;
            }
            #pragma unroll
            for (int bl = 0; bl < 8; bl++) red[hh2][bl][nl] = acc[bl];
            __syncthreads();
            for (int i = tid; i < 1024; i += 256) {
                const int bl = i >> 7, nl2 = i & 127;
                const int b = bg * 8 + bl;
                opp[((size_t)(b * 8 + c_hc)) * HID + c_nc * 128 + nl2] =
                    red[0][bl][nl2] + red[1][bl][nl2];
            }
        }
        bgroup_barrier(ctr, gen);
    }

    // tail: out row NX-1 = sum_hc opp + bV
    if (tid < 128) {
        const int idx = gi * 128 + tid;            // 0..8191 over the group
        const int bl = idx >> 10, n = idx & (HID - 1);
        const int b = bg * 8 + bl;
        float v = bV[n];
        const float* __restrict__ p = opp + ((size_t)b * 8) * HID + n;
        #pragma unroll
        for (int hc = 0; hc < 8; hc++) v += p[(size_t)hc * HID];
        out[((size_t)(b * NX + NX - 1)) * HID + n] = v;
    }
}

// ---------------------------------------------------------------------------
extern "C" void kernel_launch(void* const* d_in, const int* in_sizes, int n_in,
                              void* d_out, int out_size, void* d_ws, size_t ws_size,
                              hipStream_t stream)
{
    const float* hidden = (const float*)d_in[1];
    const float* q      = (const float*)d_in[2];
    const float* WK     = (const float*)d_in[3];
    const float* WV     = (const float*)d_in[5];
    const float* bV     = (const float*)d_in[6];
    float* out = (float*)d_out;

    char* ws = (char*)d_ws;
    float*    WVT = (float*)(ws);                          // 4 MiB
    float*    yp  = (float*)(ws + (4  << 20));             // 2 MiB
    float*    zp  = (float*)(ws + (6  << 20));             // 2 MiB
    float*    opp = (float*)(ws + (8  << 20));             // 2 MiB
    float*    ml  = (float*)(ws + (10 << 20));             // 4 KiB
    unsigned* bar = (unsigned*)(ws + (10 << 20) + (64 << 10));  // 1 KiB

    hipMemsetAsync(bar, 0, 8 * 32 * sizeof(unsigned), stream);
    transpose_k<<<dim3(32, 32), 256, 0, stream>>>(WV, WVT);
    genxs_persistent<<<NBLK, 256, 0, stream>>>(
        hidden, q, WK, WVT, bV, out, yp, zp, ml, opp, bar);
}

// Round 10
// 456.542 us; speedup vs baseline: 1.5721x; 1.5721x over previous
//
#include <hip/hip_runtime.h>

#define SEQ   512
#define BATCH 64
#define HID   1024
#define NX    8
#define SG    16     // s-groups per batch (attention); 32 rows each
#define SB    8      // rows per register batch
#define NBAT  4      // 4*8 = 32 rows per attn block

// ---------------------------------------------------------------------------
// WVT[h][n] = WV[n][h]  (one-time 32x32 tiled transpose)
// ---------------------------------------------------------------------------
__global__ __launch_bounds__(256) void transpose_k(
    const float* __restrict__ in, float* __restrict__ outT)
{
    __shared__ float tile[32][33];
    const int bx = blockIdx.x * 32, by = blockIdx.y * 32;
    const int tx = threadIdx.x & 31, ty = threadIdx.x >> 5;
    #pragma unroll
    for (int r = ty; r < 32; r += 8)
        tile[r][tx] = in[(size_t)(by + r) * HID + bx + tx];
    __syncthreads();
    #pragma unroll
    for (int r = ty; r < 32; r += 8)
        outT[(size_t)(bx + r) * HID + by + tx] = tile[tx][r];
}

// ---------------------------------------------------------------------------
// gemv_y: y[b, n] = sum_j x[b,j] * WK[j,n]   COMPLETE output.
// grid dim3(b=64, nc=32): consecutive blockIdx.x = same nc, different b ->
// same 128KB WK chunk hits L2 8x per XCD.
// x = opfull + bV (q at t==1) staged in LDS; nc==0 writes out row t-1.
// ---------------------------------------------------------------------------
__global__ __launch_bounds__(256) void gemv_y_kernel(
    const float* __restrict__ WK, const float* __restrict__ q,
    const float* __restrict__ opfull, const float* __restrict__ bV,
    float* __restrict__ out, int t, float* __restrict__ y)
{
    __shared__ float xs[HID];
    __shared__ float red[8][32];
    const int b = blockIdx.x, nc = blockIdx.y;
    const int tid = threadIdx.x;
    const int h4 = tid * 4;

    {
        float4 v;
        if (t == 1) {
            v = *(const float4*)(q + (size_t)b * HID + h4);
        } else {
            float4 o  = *(const float4*)(opfull + (size_t)b * HID + h4);
            float4 bb = *(const float4*)(bV + h4);
            v.x = o.x + bb.x; v.y = o.y + bb.y;
            v.z = o.z + bb.z; v.w = o.w + bb.w;
        }
        *(float4*)(xs + h4) = v;
        if (nc == 0)
            *(float4*)(out + ((size_t)(b * NX + t - 1)) * HID + h4) = v;
    }
    __syncthreads();

    const int nl = tid & 31, jg = tid >> 5;
    const int n = nc * 32 + nl;
    const float* __restrict__ wp = WK + (size_t)(jg * 128) * HID + n;
    const float* __restrict__ xr = xs + jg * 128;
    float acc = 0.f;
    #pragma unroll 8
    for (int jj = 0; jj < 128; jj++)
        acc += xr[jj] * wp[(size_t)jj * HID];
    red[jg][nl] = acc;
    __syncthreads();
    if (tid < 32) {
        float s = 0.f;
        #pragma unroll
        for (int g = 0; g < 8; g++) s += red[g][tid];
        y[(size_t)b * HID + nc * 32 + tid] = s;
    }
}

// ---------------------------------------------------------------------------
// fused_attn: grid dim3(sg=16, b=64). 32 rows per block, online (m,l) flash,
// hidden rows live in registers (float4 slice per thread).
// zp[b,sg,:] unnormalized; ml[b,sg] = (m, l).
// ---------------------------------------------------------------------------
__global__ __launch_bounds__(256) void fused_attn_kernel(
    const float* __restrict__ hidden, const float* __restrict__ y,
    float* __restrict__ zp, float* __restrict__ ml)
{
    const int sg = blockIdx.x, b = blockIdx.y;
    const int tid = threadIdx.x;
    const int lane = tid & 63, w = tid >> 6;
    const int h4 = tid * 4;

    __shared__ float part[4][SB];

    const float4 yv = *(const float4*)(y + (size_t)b * HID + h4);
    float m = -1e30f, l = 0.f;
    float4 acc = {0.f, 0.f, 0.f, 0.f};

    #pragma unroll
    for (int bb = 0; bb < NBAT; bb++) {
        float4 hv[SB];
        float p[SB];
        #pragma unroll
        for (int r = 0; r < SB; r++) {
            const int s = sg * 32 + bb * SB + r;
            hv[r] = *(const float4*)(hidden + ((size_t)s * BATCH + b) * HID + h4);
            p[r] = hv[r].x * yv.x + hv[r].y * yv.y
                 + hv[r].z * yv.z + hv[r].w * yv.w;
        }
        #pragma unroll
        for (int r = 0; r < SB; r++) {
            float s = p[r];
            #pragma unroll
            for (int off = 32; off; off >>= 1) s += __shfl_xor(s, off);
            if (lane == 0) part[w][r] = s;
        }
        __syncthreads();
        float sc[SB], mb = -1e30f;
        #pragma unroll
        for (int r = 0; r < SB; r++) {
            sc[r] = part[0][r] + part[1][r] + part[2][r] + part[3][r];
            mb = fmaxf(mb, sc[r]);
        }
        __syncthreads();
        const float newm  = fmaxf(m, mb);
        const float scale = __expf(m - newm);
        l *= scale;
        acc.x *= scale; acc.y *= scale; acc.z *= scale; acc.w *= scale;
        #pragma unroll
        for (int r = 0; r < SB; r++) {
            const float we = __expf(sc[r] - newm);
            l += we;
            acc.x += we * hv[r].x; acc.y += we * hv[r].y;
            acc.z += we * hv[r].z; acc.w += we * hv[r].w;
        }
        m = newm;
    }
    *(float4*)(zp + ((size_t)(b * SG + sg)) * HID + h4) = acc;
    if (tid == 0) {
        ml[(b * SG + sg) * 2 + 0] = m;
        ml[(b * SG + sg) * 2 + 1] = l;
    }
}

// ---------------------------------------------------------------------------
// gemv_out: opfull[b, n] = sum_h z[b,h] * WVT[h,n]   COMPLETE output.
// grid dim3(b=64, nc=32) (L2-shared WVT chunks). Staging applies the global
// softmax rescale: z[h] = sum_g zp[b,g,h] e^{m_g-M} / L.
// ---------------------------------------------------------------------------
__global__ __launch_bounds__(256) void gemv_out_kernel(
    const float* __restrict__ WVT, const float* __restrict__ zp,
    const float* __restrict__ ml, float* __restrict__ opfull)
{
    __shared__ float xs[HID];
    __shared__ float red[8][32];
    __shared__ float mls[2 * SG];
    const int b = blockIdx.x, nc = blockIdx.y;
    const int tid = threadIdx.x;
    const int h4 = tid * 4;

    if (tid < 2 * SG) mls[tid] = ml[b * 2 * SG + tid];
    __syncthreads();

    {
        float M = -1e30f;
        #pragma unroll
        for (int g = 0; g < SG; g++) M = fmaxf(M, mls[2 * g]);
        float es[SG], L = 0.f;
        #pragma unroll
        for (int g = 0; g < SG; g++) {
            es[g] = __expf(mls[2 * g] - M);
            L += mls[2 * g + 1] * es[g];
        }
        const float invL = 1.0f / L;

        float4 zv = {0.f, 0.f, 0.f, 0.f};
        #pragma unroll
        for (int g = 0; g < SG; g++) {
            const float4 v = *(const float4*)(
                zp + ((size_t)(b * SG + g)) * HID + h4);
            zv.x += es[g] * v.x; zv.y += es[g] * v.y;
            zv.z += es[g] * v.z; zv.w += es[g] * v.w;
        }
        zv.x *= invL; zv.y *= invL; zv.z *= invL; zv.w *= invL;
        *(float4*)(xs + h4) = zv;
    }
    __syncthreads();

    const int nl = tid & 31, hg = tid >> 5;
    const int n = nc * 32 + nl;
    const float* __restrict__ wp = WVT + (size_t)(hg * 128) * HID + n;
    const float* __restrict__ zr = xs + hg * 128;
    float acc = 0.f;
    #pragma unroll 8
    for (int hh = 0; hh < 128; hh++)
        acc += zr[hh] * wp[(size_t)hh * HID];
    red[hg][nl] = acc;
    __syncthreads();
    if (tid < 32) {
        float s = 0.f;
        #pragma unroll
        for (int g = 0; g < 8; g++) s += red[g][tid];
        opfull[(size_t)b * HID + nc * 32 + tid] = s;
    }
}

// final output row t=NX-1: out = opfull + bias
__global__ __launch_bounds__(256) void final_out_kernel(
    const float* __restrict__ opfull, const float* __restrict__ bias,
    float* __restrict__ out)
{
    const int idx = blockIdx.x * 256 + threadIdx.x;
    const int b = idx >> 10, n = idx & (HID - 1);
    out[((size_t)(b * NX + NX - 1)) * HID + n] = opfull[idx] + bias[n];
}

// ---------------------------------------------------------------------------
extern "C" void kernel_launch(void* const* d_in, const int* in_sizes, int n_in,
                              void* d_out, int out_size, void* d_ws, size_t ws_size,
                              hipStream_t stream)
{
    const float* hidden = (const float*)d_in[1];
    const float* q      = (const float*)d_in[2];
    const float* WK     = (const float*)d_in[3];
    const float* WV     = (const float*)d_in[5];
    const float* bV     = (const float*)d_in[6];
    float* out = (float*)d_out;

    char* ws = (char*)d_ws;
    float* WVT    = (float*)(ws);                              // 4 MiB
    float* zp     = (float*)(ws + (4 << 20));                  // 4 MiB
    float* y      = (float*)(ws + (8 << 20));                  // 256 KiB
    float* opfull = (float*)(ws + (8 << 20) + (256 << 10));    // 256 KiB
    float* ml     = (float*)(ws + (8 << 20) + (512 << 10));    // 8 KiB

    transpose_k<<<dim3(32, 32), 256, 0, stream>>>(WV, WVT);

    for (int t = 1; t < NX; t++) {
        gemv_y_kernel<<<dim3(BATCH, 32), 256, 0, stream>>>(
            WK, q, opfull, bV, out, t, y);
        fused_attn_kernel<<<dim3(SG, BATCH), 256, 0, stream>>>(
            hidden, y, zp, ml);
        gemv_out_kernel<<<dim3(BATCH, 32), 256, 0, stream>>>(
            WVT, zp, ml, opfull);
    }
    final_out_kernel<<<(BATCH * HID) / 256, 256, 0, stream>>>(opfull, bV, out);
}